// Round 5
// baseline (132.571 us; speedup 1.0000x reference)
//
#include <hip/hip_runtime.h>
#include <hip/hip_bf16.h>

#define NUM_D1 270
#define NUM_B  128
#define NUM_C  273
#define NUM_T  1024
#define KL     1024      // K*K = 32*32
#define TW     320       // trig table padded width
#define CP     288       // padded C for a[] (9 * 32)
#define CW     296       // W/X LDS + wg row stride in elems (592 B = 148 dw == 20 mod 32)
#define ROWB   (CW * 2)  // 592 bytes

#define WT_BYTES (144 * ROWB)              // 85,248
#define XB_BYTES (64 * ROWB)               // 37,888
#define LDS3_TOTAL (WT_BYTES + 2 * XB_BYTES)  // 161,024 <= 163,840

typedef float f32x4 __attribute__((ext_vector_type(4)));
typedef __bf16 bf16x8 __attribute__((ext_vector_type(8)));
typedef unsigned short u16x8 __attribute__((ext_vector_type(8)));

static __device__ __forceinline__ unsigned short f2bf(float f) {
  unsigned u = __float_as_uint(f);
  unsigned r = (u + 0x7fffu + ((u >> 16) & 1u)) >> 16;   // RNE
  return (unsigned short)r;
}

// Kernel 0: trig tables cos/sin(2*pi*(k*x + l*y)) for all (kl, c)
__global__ __launch_bounds__(256) void k_trig(const float* __restrict__ loc,
                                              float* __restrict__ cosT,
                                              float* __restrict__ sinT) {
  int idx = blockIdx.x * 256 + threadIdx.x;   // 0 .. 1024*320-1
  int kl = idx / TW;
  int c  = idx - kl * TW;
  float cv = 0.f, sv = 0.f;
  if (c < NUM_C) {
    float x = loc[2 * c], y = loc[2 * c + 1];
    float kf = (float)(kl >> 5), lf = (float)(kl & 31);
    float ph = 6.283185307179586f * (kf * x + lf * y);
    sincosf(ph, &sv, &cv);
  }
  cosT[idx] = cv;
  sinT[idx] = sv;
}

// Kernel 1: a[j,c] = sum_kl z_re[j,kl]*cos[kl,c] + z_im[j,kl]*sin[kl,c]
__global__ __launch_bounds__(1024) void k_agemm(const float* __restrict__ z_re,
                                                const float* __restrict__ z_im,
                                                const float* __restrict__ cosT,
                                                const float* __restrict__ sinT,
                                                float* __restrict__ a) {
  __shared__ float sm[4][8][64];
  int tid = threadIdx.x;
  int lane = tid & 63;
  int g = tid >> 6;            // 0..15
  int p = g >> 3;              // 0..1
  int q = g & 7;               // 0..7
  int jb = blockIdx.x;         // 0..67
  int cb = blockIdx.y;         // 0..4
  int c = cb * 64 + lane;      // < 320, in-bounds of padded table
  int j_a = jb * 4 + p;        // <= 269
  int j_b = j_a + 2;           // <= 271
  int jeb = (j_b < NUM_D1) ? j_b : 0;
  const float* zr0 = z_re + (size_t)j_a * KL;
  const float* zi0 = z_im + (size_t)j_a * KL;
  const float* zr1 = z_re + (size_t)jeb * KL;
  const float* zi1 = z_im + (size_t)jeb * KL;
  float a0 = 0.f, a1 = 0.f;
  int k0 = q * 128;
  #pragma unroll 4
  for (int kk = k0; kk < k0 + 128; ++kk) {
    float cv = cosT[kk * TW + c];
    float sv = sinT[kk * TW + c];
    a0 = fmaf(zr0[kk], cv, a0);
    a0 = fmaf(zi0[kk], sv, a0);
    a1 = fmaf(zr1[kk], cv, a1);
    a1 = fmaf(zi1[kk], sv, a1);
  }
  sm[p][q][lane] = a0;
  sm[p + 2][q][lane] = a1;
  __syncthreads();
  if (tid < 256) {
    int jl = tid >> 6;          // 0..3
    int l2 = tid & 63;
    int j = jb * 4 + jl;
    int c2 = cb * 64 + l2;
    float s = 0.f;
    #pragma unroll
    for (int qq = 0; qq < 8; ++qq) s += sm[jl][qq][l2];
    if (j < NUM_D1 && c2 < NUM_C) a[j * CP + c2] = s;
  }
}

// Kernel 2: w[j,:] = softmax_c(a[j,:]) -> bf16 into wg[288 rows][CW=296 stride], zero-padded
__global__ __launch_bounds__(256) void k_softmax(const float* __restrict__ a,
                                                 unsigned short* __restrict__ wg) {
  int wv = threadIdx.x >> 6;
  int lane = threadIdx.x & 63;
  int j = blockIdx.x * 4 + wv;   // < 288 (grid 72)
  if (j >= NUM_D1) {
    for (int c = lane; c < CW; c += 64) wg[j * CW + c] = 0;
    return;
  }
  float e[5];
  float s = 0.f;
  #pragma unroll
  for (int qq = 0; qq < 5; ++qq) {
    int c = qq * 64 + lane;
    float v = 0.f;
    if (c < NUM_C) v = expf(a[j * CP + c]);
    e[qq] = v;
    s += v;
  }
  #pragma unroll
  for (int o = 32; o > 0; o >>= 1) s += __shfl_xor(s, o, 64);
  float inv = 1.0f / s;
  #pragma unroll
  for (int qq = 0; qq < 5; ++qq) {
    int c = qq * 64 + lane;
    if (c < CW) wg[j * CW + c] = (c < NUM_C) ? f2bf(e[qq] * inv) : (unsigned short)0;
  }
}

// Kernel 3: out[b,j,t] = sum_c w[j,c] * X[b,c,t]  (bf16 MFMA, fp32 accum)
// Persistent pipelined: grid (2 jh, 128 b) = 256 blocks = 1/CU, 768 thr / 12 waves.
// W-half (144x296 bf16) resident in LDS; 16 t-tiles of 64 with double-buffered X^T;
// next tile's global loads issued before current tile's compute (async-split).
__global__ __launch_bounds__(768) void k_out3(const float* __restrict__ X,
                                              const unsigned short* __restrict__ wg,
                                              float* __restrict__ out) {
  extern __shared__ char lds[];
  char* WTb = lds;
  char* XA  = lds + WT_BYTES;
  char* XBf = lds + WT_BYTES + XB_BYTES;

  const int tid = threadIdx.x;
  const int wv = tid >> 6, lane = tid & 63;
  const int rlo = lane & 15, kg = lane >> 4;
  const int jh = blockIdx.x;       // 0..1
  const int b  = blockIdx.y;       // 0..127
  const float* Xb = X + (size_t)b * (NUM_C * NUM_T);
  const int c8 = tid >> 4;         // staging: 16B c-group (use < 36)
  const int t4 = tid & 15;         // staging: t-quad
  const bool stg = (c8 < 36);      // 576 staging threads

  // ---- prologue: issue W-half + X tile 0 loads, then write LDS ----
  f32x4 v[8];
  if (stg) {
    #pragma unroll
    for (int e = 0; e < 8; ++e) {
      int c = c8 * 8 + e;
      if (c < NUM_C) {
        v[e] = *(const f32x4*)(Xb + (size_t)c * NUM_T + t4 * 4);
      } else {
        v[e][0] = v[e][1] = v[e][2] = v[e][3] = 0.f;
      }
    }
  }
  {
    const char* wsrc = (const char*)wg + (size_t)jh * WT_BYTES;
    uint4 wv4[7];
    #pragma unroll
    for (int i = 0; i < 7; ++i) {
      int off = (tid + i * 768) * 16;
      if (off < WT_BYTES) wv4[i] = *(const uint4*)(wsrc + off);
    }
    #pragma unroll
    for (int i = 0; i < 7; ++i) {
      int off = (tid + i * 768) * 16;
      if (off < WT_BYTES) *(uint4*)(WTb + off) = wv4[i];
    }
  }
  if (stg) {
    #pragma unroll
    for (int f = 0; f < 4; ++f) {
      int tw = t4 * 4 + f;
      u16x8 pk;
      #pragma unroll
      for (int e = 0; e < 8; ++e) pk[e] = f2bf(v[e][f]);
      *(u16x8*)(XA + tw * ROWB + ((c8 * 16) ^ ((t4 & 3) << 4))) = pk;
    }
  }
  __syncthreads();

  const int tt = wv & 3, jq = wv >> 2;   // 4 t-slices x 3 j-groups
  const int t = tt * 16 + rlo;
  const int sw = ((t >> 2) & 3) << 4;

  for (int it = 0; it < 16; ++it) {
    const int t0 = it * 64;
    char* xcur = (it & 1) ? XBf : XA;
    char* xnxt = (it & 1) ? XA : XBf;

    // prefetch next X tile into registers (HBM latency hides under compute)
    const bool pf = stg && (it < 15);
    if (pf) {
      #pragma unroll
      for (int e = 0; e < 8; ++e) {
        int c = c8 * 8 + e;
        if (c < NUM_C) {
          v[e] = *(const f32x4*)(Xb + (size_t)c * NUM_T + t0 + 64 + t4 * 4);
        } else {
          v[e][0] = v[e][1] = v[e][2] = v[e][3] = 0.f;
        }
      }
    }

    // ---- compute current tile ----
    bf16x8 bfr[9];
    #pragma unroll
    for (int ks = 0; ks < 9; ++ks)
      bfr[ks] = *(const bf16x8*)(xcur + t * ROWB + ((ks * 64 + kg * 16) ^ sw));

    f32x4 acc[3];
    #pragma unroll
    for (int jt = 0; jt < 3; ++jt)
      acc[jt][0] = acc[jt][1] = acc[jt][2] = acc[jt][3] = 0.f;

    #pragma unroll
    for (int ks = 0; ks < 9; ++ks) {
      #pragma unroll
      for (int jt = 0; jt < 3; ++jt) {
        bf16x8 afr = *(const bf16x8*)(WTb +
            (size_t)((jq * 3 + jt) * 16 + rlo) * ROWB + kg * 16 + ks * 64);
        acc[jt] = __builtin_amdgcn_mfma_f32_16x16x32_bf16(afr, bfr[ks], acc[jt], 0, 0, 0);
      }
    }

    // store: C layout col = rlo (t), row = kg*4 + r (j within 16-tile); nt to spare caches
    #pragma unroll
    for (int jt = 0; jt < 3; ++jt) {
      #pragma unroll
      for (int r = 0; r < 4; ++r) {
        int j = jh * 144 + (jq * 3 + jt) * 16 + kg * 4 + r;
        if (j < NUM_D1)
          __builtin_nontemporal_store(acc[jt][r],
              out + ((size_t)b * NUM_D1 + j) * NUM_T + t0 + t);
      }
    }

    if (it < 15) {
      if (pf) {
        #pragma unroll
        for (int f = 0; f < 4; ++f) {
          int tw = t4 * 4 + f;
          u16x8 pk;
          #pragma unroll
          for (int e = 0; e < 8; ++e) pk[e] = f2bf(v[e][f]);
          *(u16x8*)(xnxt + tw * ROWB + ((c8 * 16) ^ ((t4 & 3) << 4))) = pk;
        }
      }
      __syncthreads();
    }
  }
}

extern "C" void kernel_launch(void* const* d_in, const int* in_sizes, int n_in,
                              void* d_out, int out_size, void* d_ws, size_t ws_size,
                              hipStream_t stream) {
  const float* X   = (const float*)d_in[0];
  const float* loc = (const float*)d_in[1];
  const float* zre = (const float*)d_in[2];
  const float* zim = (const float*)d_in[3];
  float* out = (float*)d_out;
  char* ws = (char*)d_ws;
  float* cosT = (float*)(ws);
  float* sinT = (float*)(ws + 1310720);
  float* a    = (float*)(ws + 2621440);
  unsigned short* wgp = (unsigned short*)(ws + 2934784);   // [288][296] bf16 = 170,496 B

  (void)hipFuncSetAttribute((const void*)k_out3,
                            hipFuncAttributeMaxDynamicSharedMemorySize, LDS3_TOTAL);

  hipLaunchKernelGGL(k_trig,    dim3(1280),   dim3(256),  0, stream, loc, cosT, sinT);
  hipLaunchKernelGGL(k_agemm,   dim3(68, 5),  dim3(1024), 0, stream, zre, zim, cosT, sinT, a);
  hipLaunchKernelGGL(k_softmax, dim3(72),     dim3(256),  0, stream, a, wgp);
  hipLaunchKernelGGL(k_out3,    dim3(2, 128), dim3(768),  LDS3_TOTAL, stream, X, wgp, out);
}